// Round 4
// baseline (893.190 us; speedup 1.0000x reference)
//
#include <hip/hip_runtime.h>
#include <hip/hip_bf16.h>

typedef __attribute__((ext_vector_type(4))) float  f32x4;
typedef __attribute__((ext_vector_type(8))) short  bf16x8;
typedef __attribute__((ext_vector_type(4))) short  short4_t;
typedef unsigned short u16;

#define SCALE_Q 0.17677669529663687f   // 32^-0.5

// native RNE float->bf16 (compiler packs pairs into v_cvt_pk_bf16_f32)
__device__ __forceinline__ short bfc(float f) {
    __bf16 b = (__bf16)f;
    union { __bf16 b; short s; } u; u.b = b; return u.s;
}

__device__ __forceinline__ bf16x8 pack8(f32x4 a, f32x4 b) {
    bf16x8 o;
    o[0] = bfc(a[0]); o[1] = bfc(a[1]); o[2] = bfc(a[2]); o[3] = bfc(a[3]);
    o[4] = bfc(b[0]); o[5] = bfc(b[1]); o[6] = bfc(b[2]); o[7] = bfc(b[3]);
    return o;
}

// ---------------------------------------------------------------------------
// fp32 -> bf16 convert (weights only), 8 elems/thread
// ---------------------------------------------------------------------------
__global__ __launch_bounds__(256) void cvt_kernel(
        const float* __restrict__ s, u16* __restrict__ d, int n8)
{
    const int i = blockIdx.x * 256 + threadIdx.x;
    if (i >= n8) return;
    const float4* sp = (const float4*)s + (size_t)i * 2;
    const float4 a = sp[0], b = sp[1];
    bf16x8 o;
    o[0] = bfc(a.x); o[1] = bfc(a.y); o[2] = bfc(a.z); o[3] = bfc(a.w);
    o[4] = bfc(b.x); o[5] = bfc(b.y); o[6] = bfc(b.z); o[7] = bfc(b.w);
    *((bf16x8*)d + i) = o;
}

// ---------------------------------------------------------------------------
// cwb[w][h][i][j] = bias_table[REL_IDX[i][j]][h] + mask[w][i][j]   (fp32)
// ---------------------------------------------------------------------------
__global__ __launch_bounds__(256) void cwb_kernel(
        const float* __restrict__ bias_table,   // [225][16]
        const float* __restrict__ mask,         // [64][64][64]
        float* __restrict__ cwb)                // [64][16][64][64]
{
    const int wh = blockIdx.x;          // w*16 + h
    const int w = wh >> 4, h = wh & 15;
    for (int e = threadIdx.x; e < 4096; e += 256) {
        const int i = e >> 6, j = e & 63;
        const int rel = ((i >> 3) - (j >> 3) + 7) * 15 + (i & 7) - (j & 7) + 7;
        cwb[(size_t)wh * 4096 + e] = bias_table[rel * 16 + h] + mask[(size_t)w * 4096 + e];
    }
}

// ---------------------------------------------------------------------------
// Streaming GEMM, no LDS, no barriers. One 64x64 output tile per wave.
// C[65536,512] = A[65536,512] @ W[512,512]b16^T + bias, * scale.
// MFMA fragments loaded DIRECTLY global->VGPR (8 contiguous k-elems/lane);
// 2-stage software pipeline (load ks+1 while computing ks).
// A fragment addrs are identical across the 4 waves of a block (same m-panel,
// different n) -> L1 broadcast. W is 512KB bf16 -> L2-resident.
// AFP32: 1 = A fp32 (convert in-register), 0 = A bf16.
// OMODE: 0 = bf16 out [b][h][t][d]; 1 = bf16 out [b][h][d][t]; 2 = fp32 [m][n]
// ---------------------------------------------------------------------------
template<int AFP32, int OMODE>
__global__ __launch_bounds__(256) void gemm_stream(
        const void* __restrict__ Aptr, const u16* __restrict__ Wb,
        const float* __restrict__ bias, float scale, void* __restrict__ outp)
{
    // XCD swizzle (2048 wgs, 8 XCDs, 256 contiguous per XCD)
    const int bidx = (blockIdx.x & 7) * 256 + (blockIdx.x >> 3);
    const int wv = threadIdx.x >> 6, lane = threadIdx.x & 63;
    const int g = lane >> 4, ln = lane & 15;
    const int wt = bidx * 4 + wv;          // wave tile id, 8192 total
    const int m0 = (wt >> 3) << 6;
    const int n0 = (wt & 7) << 6;
    const int ko = g << 3;                 // lane k-offset within 32-slice

    f32x4 acc[4][4];
#pragma unroll
    for (int i = 0; i < 4; i++)
#pragma unroll
        for (int j = 0; j < 4; j++) acc[i][j] = {0.f, 0.f, 0.f, 0.f};

    const u16* bpm[4];
#pragma unroll
    for (int nt = 0; nt < 4; nt++)
        bpm[nt] = Wb + (size_t)(n0 + nt * 16 + ln) * 512 + ko;

    if (AFP32) {
        const float* A = (const float*)Aptr;
        const float* apm[4];
#pragma unroll
        for (int mt = 0; mt < 4; mt++)
            apm[mt] = A + (size_t)(m0 + mt * 16 + ln) * 512 + ko;

#define LOADF(KS, LO, HI, BF) do {                                          \
    _Pragma("unroll")                                                       \
    for (int mt = 0; mt < 4; mt++) {                                        \
        LO[mt] = *(const f32x4*)(apm[mt] + (KS) * 32);                      \
        HI[mt] = *(const f32x4*)(apm[mt] + (KS) * 32 + 4);                  \
    }                                                                       \
    _Pragma("unroll")                                                       \
    for (int nt = 0; nt < 4; nt++)                                          \
        BF[nt] = *(const bf16x8*)(bpm[nt] + (KS) * 32);                     \
} while (0)

#define COMPF(LO, HI, BF) do {                                              \
    bf16x8 aw_[4];                                                          \
    _Pragma("unroll")                                                       \
    for (int mt = 0; mt < 4; mt++) aw_[mt] = pack8(LO[mt], HI[mt]);         \
    _Pragma("unroll")                                                       \
    for (int mt = 0; mt < 4; mt++)                                          \
        _Pragma("unroll")                                                   \
        for (int nt = 0; nt < 4; nt++)                                      \
            acc[mt][nt] = __builtin_amdgcn_mfma_f32_16x16x32_bf16(          \
                aw_[mt], BF[nt], acc[mt][nt], 0, 0, 0);                     \
} while (0)

        f32x4 lo0[4], hi0[4], lo1[4], hi1[4];
        bf16x8 b0[4], b1[4];
        LOADF(0, lo0, hi0, b0);
#pragma unroll
        for (int kp = 0; kp < 8; kp++) {
            LOADF(2 * kp + 1, lo1, hi1, b1);
            COMPF(lo0, hi0, b0);
            if (kp < 7) LOADF(2 * kp + 2, lo0, hi0, b0);
            COMPF(lo1, hi1, b1);
        }
    } else {
        const u16* A = (const u16*)Aptr;
        const u16* apm[4];
#pragma unroll
        for (int mt = 0; mt < 4; mt++)
            apm[mt] = A + (size_t)(m0 + mt * 16 + ln) * 512 + ko;

#define LOADB(KS, AB, BF) do {                                              \
    _Pragma("unroll")                                                       \
    for (int mt = 0; mt < 4; mt++)                                          \
        AB[mt] = *(const bf16x8*)(apm[mt] + (KS) * 32);                     \
    _Pragma("unroll")                                                       \
    for (int nt = 0; nt < 4; nt++)                                          \
        BF[nt] = *(const bf16x8*)(bpm[nt] + (KS) * 32);                     \
} while (0)

#define COMPB(AB, BF) do {                                                  \
    _Pragma("unroll")                                                       \
    for (int mt = 0; mt < 4; mt++)                                          \
        _Pragma("unroll")                                                   \
        for (int nt = 0; nt < 4; nt++)                                      \
            acc[mt][nt] = __builtin_amdgcn_mfma_f32_16x16x32_bf16(          \
                AB[mt], BF[nt], acc[mt][nt], 0, 0, 0);                      \
} while (0)

        bf16x8 a0[4], a1[4], b0[4], b1[4];
        LOADB(0, a0, b0);
#pragma unroll
        for (int kp = 0; kp < 8; kp++) {
            LOADB(2 * kp + 1, a1, b1);
            COMPB(a0, b0);
            if (kp < 7) LOADB(2 * kp + 2, a0, b0);
            COMPB(a1, b1);
        }
    }

    // ---- epilogue: bias, scale, store ----
#pragma unroll
    for (int mt = 0; mt < 4; mt++) {
#pragma unroll
        for (int nt = 0; nt < 4; nt++) {
            const int n = n0 + (nt << 4) + ln;
            const float bv = bias[n];
            const int mbase = m0 + (mt << 4) + (g << 2);
            if (OMODE == 0) {
#pragma unroll
                for (int r = 0; r < 4; r++) {
                    const int m = mbase + r;
                    const int b = m >> 6, tt = m & 63, hh = n >> 5, d = n & 31;
                    ((u16*)outp)[((size_t)(b * 16 + hh) * 64 + tt) * 32 + d] =
                        (u16)bfc((acc[mt][nt][r] + bv) * scale);
                }
            } else if (OMODE == 1) {
                short4_t hq;
#pragma unroll
                for (int r = 0; r < 4; r++) hq[r] = bfc((acc[mt][nt][r] + bv) * scale);
                const int b = mbase >> 6, tt = mbase & 63, hh = n >> 5, d = n & 31;
                *(short4_t*)&((u16*)outp)[((size_t)(b * 16 + hh) * 32 + d) * 64 + tt] = hq;
            } else {
#pragma unroll
                for (int r = 0; r < 4; r++) {
                    const int m = mbase + r;
                    ((float*)outp)[(size_t)m * 512 + n] = (acc[mt][nt][r] + bv) * scale;
                }
            }
        }
    }
}

// ---------------------------------------------------------------------------
// Attention: 4 waves/block, one (b,h) per wave. S^T = K·Q^T via mfma(K,Q);
// softmax over j = local reduce + shfl_xor 16/32; P -> private LDS region
// bf16 [i][j] XOR-swizzled; O^T = V^T·P.
// qh,kh: [b][h][t][d] bf16 ; vt: [b][h][d][t] bf16 ; x out: [b][t][h*32+d] bf16
// ---------------------------------------------------------------------------
__global__ __launch_bounds__(256) void attn_kernel(
        const u16* __restrict__ qh, const u16* __restrict__ kh,
        const u16* __restrict__ vt, const float* __restrict__ cwb,
        u16* __restrict__ xout)
{
    __shared__ __align__(16) u16 P[16384];   // 4 waves x 8 KB

    const int wv = threadIdx.x >> 6;
    const int bid = (blockIdx.x << 2) + wv;     // b*16 + h
    const int b = bid >> 4, h = bid & 15, w = b & 63;
    const int lane = threadIdx.x & 63, g = lane >> 4, ln = lane & 15;
    const size_t base = (size_t)bid * 2048;
    u16* Pw = &P[wv << 12];

    bf16x8 kf[4], qf[4];
#pragma unroll
    for (int mt = 0; mt < 4; mt++)
        kf[mt] = *(const bf16x8*)&kh[base + (mt * 16 + ln) * 32 + g * 8];
#pragma unroll
    for (int nt = 0; nt < 4; nt++)
        qf[nt] = *(const bf16x8*)&qh[base + (nt * 16 + ln) * 32 + g * 8];

    f32x4 acc[4][4];   // acc[mt][nt]: rows j = mt*16+g*4+r, cols i = nt*16+ln
#pragma unroll
    for (int i = 0; i < 4; i++)
#pragma unroll
        for (int j = 0; j < 4; j++) acc[i][j] = {0.f, 0.f, 0.f, 0.f};

#pragma unroll
    for (int mt = 0; mt < 4; mt++)
#pragma unroll
        for (int nt = 0; nt < 4; nt++)
            acc[mt][nt] = __builtin_amdgcn_mfma_f32_16x16x32_bf16(
                kf[mt], qf[nt], acc[mt][nt], 0, 0, 0);

    const float* cw = cwb + (size_t)(w * 16 + h) * 4096;
#pragma unroll
    for (int nt = 0; nt < 4; nt++) {
        const int i = nt * 16 + ln;
#pragma unroll
        for (int mt = 0; mt < 4; mt++) {
            const float4 bm = *(const float4*)&cw[i * 64 + mt * 16 + (g << 2)];
            acc[mt][nt][0] += bm.x; acc[mt][nt][1] += bm.y;
            acc[mt][nt][2] += bm.z; acc[mt][nt][3] += bm.w;
        }
    }

#pragma unroll
    for (int nt = 0; nt < 4; nt++) {
        float mx = acc[0][nt][0];
#pragma unroll
        for (int mt = 0; mt < 4; mt++)
#pragma unroll
            for (int r = 0; r < 4; r++) mx = fmaxf(mx, acc[mt][nt][r]);
        mx = fmaxf(mx, __shfl_xor(mx, 16));
        mx = fmaxf(mx, __shfl_xor(mx, 32));
        float sum = 0.f;
#pragma unroll
        for (int mt = 0; mt < 4; mt++)
#pragma unroll
            for (int r = 0; r < 4; r++) {
                const float p = __expf(acc[mt][nt][r] - mx);
                acc[mt][nt][r] = p;
                sum += p;
            }
        sum += __shfl_xor(sum, 16);
        sum += __shfl_xor(sum, 32);
        const float rs = 1.0f / sum;
        const int i = nt * 16 + ln;
#pragma unroll
        for (int mt = 0; mt < 4; mt++) {
            short4_t hq;
#pragma unroll
            for (int r = 0; r < 4; r++) hq[r] = bfc(acc[mt][nt][r] * rs);
            const int idx = (i * 64 + mt * 16 + (g << 2)) ^ ((i & 7) << 3);
            *(short4_t*)&Pw[idx] = hq;
        }
    }
    __syncthreads();

    f32x4 oacc[2][4];
#pragma unroll
    for (int i = 0; i < 2; i++)
#pragma unroll
        for (int j = 0; j < 4; j++) oacc[i][j] = {0.f, 0.f, 0.f, 0.f};

#pragma unroll
    for (int ks = 0; ks < 2; ks++) {
        bf16x8 vf[2], pf[4];
#pragma unroll
        for (int mt = 0; mt < 2; mt++)
            vf[mt] = *(const bf16x8*)&vt[base + (mt * 16 + ln) * 64 + ks * 32 + g * 8];
#pragma unroll
        for (int nt = 0; nt < 4; nt++) {
            const int i = nt * 16 + ln;
            pf[nt] = *(const bf16x8*)&Pw[(i * 64 + ks * 32 + g * 8) ^ ((i & 7) << 3)];
        }
#pragma unroll
        for (int mt = 0; mt < 2; mt++)
#pragma unroll
            for (int nt = 0; nt < 4; nt++)
                oacc[mt][nt] = __builtin_amdgcn_mfma_f32_16x16x32_bf16(
                    vf[mt], pf[nt], oacc[mt][nt], 0, 0, 0);
    }

#pragma unroll
    for (int mt = 0; mt < 2; mt++) {
#pragma unroll
        for (int nt = 0; nt < 4; nt++) {
            const int i = nt * 16 + ln, d0 = mt * 16 + (g << 2);
            short4_t hq;
#pragma unroll
            for (int r = 0; r < 4; r++) hq[r] = bfc(oacc[mt][nt][r]);
            *(short4_t*)&xout[((size_t)b * 64 + i) * 512 + h * 32 + d0] = hq;
        }
    }
}

// ---------------------------------------------------------------------------
extern "C" void kernel_launch(void* const* d_in, const int* in_sizes, int n_in,
                              void* d_out, int out_size, void* d_ws, size_t ws_size,
                              hipStream_t stream) {
    const float* q    = (const float*)d_in[0];
    const float* k    = (const float*)d_in[1];
    const float* v    = (const float*)d_in[2];
    const float* mask = (const float*)d_in[3];
    const float* Wq   = (const float*)d_in[4];
    const float* bq   = (const float*)d_in[5];
    const float* Wk   = (const float*)d_in[6];
    const float* bk   = (const float*)d_in[7];
    const float* Wv   = (const float*)d_in[8];
    const float* bv   = (const float*)d_in[9];
    const float* Wp   = (const float*)d_in[10];
    const float* bp   = (const float*)d_in[11];
    const float* bias_table = (const float*)d_in[12];
    float* out = (float*)d_out;

    // ws layout (bytes): t0 (attn out) | qh | kh | vt | cwb | 4x weight bf16
    char* ws = (char*)d_ws;
    u16*   t0  = (u16*)(ws);
    u16*   qh  = (u16*)(ws + 67108864);
    u16*   kh  = (u16*)(ws + 134217728);
    u16*   vt  = (u16*)(ws + 201326592);
    float* cwb = (float*)(ws + 268435456);
    u16*   wqb = (u16*)(ws + 285212672);
    u16*   wkb = (u16*)(ws + 285736960);
    u16*   wvb = (u16*)(ws + 286261248);
    u16*   wpb = (u16*)(ws + 286785536);

    const int n8_w = (512 * 512) / 8;           // 32,768

    cwb_kernel<<<1024, 256, 0, stream>>>(bias_table, mask, cwb);
    cvt_kernel<<<n8_w / 256, 256, 0, stream>>>(Wq, wqb, n8_w);
    cvt_kernel<<<n8_w / 256, 256, 0, stream>>>(Wk, wkb, n8_w);
    cvt_kernel<<<n8_w / 256, 256, 0, stream>>>(Wv, wvb, n8_w);
    cvt_kernel<<<n8_w / 256, 256, 0, stream>>>(Wp, wpb, n8_w);

    gemm_stream<1, 0><<<2048, 256, 0, stream>>>((const void*)q, wqb, bq, SCALE_Q, (void*)qh);
    gemm_stream<1, 0><<<2048, 256, 0, stream>>>((const void*)k, wkb, bk, 1.0f,    (void*)kh);
    gemm_stream<1, 1><<<2048, 256, 0, stream>>>((const void*)v, wvb, bv, 1.0f,    (void*)vt);

    attn_kernel<<<4096, 256, 0, stream>>>(qh, kh, vt, cwb, t0);

    gemm_stream<0, 2><<<2048, 256, 0, stream>>>((const void*)t0, wpb, bp, 1.0f, (void*)out);
}

// Round 5
// 701.360 us; speedup vs baseline: 1.2735x; 1.2735x over previous
//
#include <hip/hip_runtime.h>
#include <hip/hip_bf16.h>

typedef __attribute__((ext_vector_type(4))) float  f32x4;
typedef __attribute__((ext_vector_type(8))) short  bf16x8;
typedef __attribute__((ext_vector_type(4))) short  short4_t;
typedef unsigned short u16;

#define SCALE_Q 0.17677669529663687f   // 32^-0.5

// native RNE float->bf16 (compiler packs pairs into v_cvt_pk_bf16_f32)
__device__ __forceinline__ short bfc(float f) {
    __bf16 b = (__bf16)f;
    union { __bf16 b; short s; } u; u.b = b; return u.s;
}

__device__ __forceinline__ void load_lds16(const void* g, void* l) {
    __builtin_amdgcn_global_load_lds(
        (const __attribute__((address_space(1))) void*)g,
        (__attribute__((address_space(3))) void*)l, 16, 0, 0);
}

// ---------------------------------------------------------------------------
// fp32 -> bf16 convert (activations), 8 elems/thread
// ---------------------------------------------------------------------------
__global__ __launch_bounds__(256) void cvt_kernel(
        const float* __restrict__ s, u16* __restrict__ d, int n8)
{
    const int i = blockIdx.x * 256 + threadIdx.x;
    if (i >= n8) return;
    const float4* sp = (const float4*)s + (size_t)i * 2;
    const float4 a = sp[0], b = sp[1];
    bf16x8 o;
    o[0] = bfc(a.x); o[1] = bfc(a.y); o[2] = bfc(a.z); o[3] = bfc(a.w);
    o[4] = bfc(b.x); o[5] = bfc(b.y); o[6] = bfc(b.z); o[7] = bfc(b.w);
    *((bf16x8*)d + i) = o;
}

// All four 512x512 weights in one launch: blockIdx.y selects the matrix.
__global__ __launch_bounds__(256) void wcvt_kernel(
        const float* __restrict__ w0, const float* __restrict__ w1,
        const float* __restrict__ w2, const float* __restrict__ w3,
        u16* __restrict__ d0, u16* __restrict__ d1,
        u16* __restrict__ d2, u16* __restrict__ d3)
{
    const float* s = (blockIdx.y == 0) ? w0 : (blockIdx.y == 1) ? w1
                   : (blockIdx.y == 2) ? w2 : w3;
    u16* d = (blockIdx.y == 0) ? d0 : (blockIdx.y == 1) ? d1
           : (blockIdx.y == 2) ? d2 : d3;
    const int i = blockIdx.x * 256 + threadIdx.x;   // 32768 per matrix
    const float4* sp = (const float4*)s + (size_t)i * 2;
    const float4 a = sp[0], b = sp[1];
    bf16x8 o;
    o[0] = bfc(a.x); o[1] = bfc(a.y); o[2] = bfc(a.z); o[3] = bfc(a.w);
    o[4] = bfc(b.x); o[5] = bfc(b.y); o[6] = bfc(b.z); o[7] = bfc(b.w);
    *((bf16x8*)d + i) = o;
}

// ---------------------------------------------------------------------------
// cwb[w][h][i][j] = bias_table[REL_IDX[i][j]][h] + mask[w][i][j]   (fp32)
// ---------------------------------------------------------------------------
__global__ __launch_bounds__(256) void cwb_kernel(
        const float* __restrict__ bias_table,   // [225][16]
        const float* __restrict__ mask,         // [64][64][64]
        float* __restrict__ cwb)                // [64][16][64][64]
{
    const int wh = blockIdx.x;          // w*16 + h
    const int w = wh >> 4, h = wh & 15;
    for (int e = threadIdx.x; e < 4096; e += 256) {
        const int i = e >> 6, j = e & 63;
        const int rel = ((i >> 3) - (j >> 3) + 7) * 15 + (i & 7) - (j & 7) + 7;
        cwb[(size_t)wh * 4096 + e] = bias_table[rel * 16 + h] + mask[(size_t)w * 4096 + e];
    }
}

// ---------------------------------------------------------------------------
// 256x256-tile GEMM, BK=32, 8 waves (2x4), 512 thr, double-buffered LDS with
// counted vmcnt + raw s_barrier (T3/T4): stage(kt+2) issued right after the
// barrier ending compute(kt); loads stay in flight across compute(kt+1);
// s_waitcnt vmcnt(4) (not 0) keeps the next tile's 4 loads airborne.
// C[65536,512] = A[65536,512]b16 @ W[512,512]b16^T + bias, * scale.
// LDS swizzle: 16B-block blk of row r at (blk ^ (r&3)); staging pre-swizzles
// the GLOBAL source col so LDS dest stays linear (global_load_lds rule).
// OMODE: 0 = bf16 out [b][h][t][d]; 1 = bf16 out [b][h][d][t]; 2 = fp32 [m][n]
// ---------------------------------------------------------------------------
template<int OMODE>
__global__ __launch_bounds__(512, 2) void gemm256(
        const u16* __restrict__ A, const u16* __restrict__ Wb,
        const float* __restrict__ bias, float scale, void* __restrict__ outp)
{
    __shared__ __align__(16) u16 As[2][8192];   // [buf][256 rows][32 k]
    __shared__ __align__(16) u16 Bs[2][8192];

    // XCD swizzle: 512 wgs, 8 XCDs, 64 contiguous per XCD
    const int wg = ((blockIdx.x & 7) << 6) + (blockIdx.x >> 3);
    const int m0 = (wg >> 1) << 8;
    const int n0 = (wg & 1) << 8;

    const int t = threadIdx.x;
    const int lane = t & 63, wv = t >> 6;
    const int g = lane >> 4, ln = lane & 15;
    const int wr = wv >> 2, wc = wv & 3;       // 2 x 4 wave grid, 128x64 each

    const u16* Ab = A  + (size_t)m0 * 512;
    const u16* Bb = Wb + (size_t)n0 * 512;

    f32x4 acc[8][4];
#pragma unroll
    for (int i = 0; i < 8; i++)
#pragma unroll
        for (int j = 0; j < 4; j++) acc[i][j] = {0.f, 0.f, 0.f, 0.f};

    // ---- staging: 4 global_load_lds per thread per K-tile ----
#define STAGE(KT, BUF) do {                                                  \
    _Pragma("unroll")                                                        \
    for (int c = 0; c < 2; c++) {                                            \
        const int bi = (c << 9) + t;          /* 16B-block 0..1023 */        \
        const int row = bi >> 2, blk = bi & 3;                               \
        const int col = ((KT) << 5) + ((blk ^ (row & 3)) << 3);              \
        load_lds16(Ab + (size_t)row * 512 + col, &As[BUF][bi << 3]);         \
        load_lds16(Bb + (size_t)row * 512 + col, &Bs[BUF][bi << 3]);         \
    }                                                                        \
} while (0)

    // ---- compute one K-tile from buf: 12 ds_read_b128, 32 MFMA per wave ----
#define COMPUTE(BUF) do {                                                    \
    bf16x8 bfr[4];                                                           \
    _Pragma("unroll")                                                        \
    for (int nt = 0; nt < 4; nt++) {                                         \
        const int rn = (wc << 6) + (nt << 4) + ln;                           \
        bfr[nt] = *(const bf16x8*)&Bs[BUF][(rn << 5) + ((g ^ (rn & 3)) << 3)];\
    }                                                                        \
    _Pragma("unroll")                                                        \
    for (int mh = 0; mh < 2; mh++) {                                         \
        bf16x8 af[4];                                                        \
        _Pragma("unroll")                                                    \
        for (int mt = 0; mt < 4; mt++) {                                     \
            const int rm = (wr << 7) + (mh << 6) + (mt << 4) + ln;           \
            af[mt] = *(const bf16x8*)&As[BUF][(rm << 5) + ((g ^ (rm & 3)) << 3)];\
        }                                                                    \
        __builtin_amdgcn_s_setprio(1);                                       \
        _Pragma("unroll")                                                    \
        for (int mt = 0; mt < 4; mt++)                                       \
            _Pragma("unroll")                                                \
            for (int nt = 0; nt < 4; nt++)                                   \
                acc[(mh << 2) + mt][nt] = __builtin_amdgcn_mfma_f32_16x16x32_bf16(\
                    af[mt], bfr[nt], acc[(mh << 2) + mt][nt], 0, 0, 0);      \
        __builtin_amdgcn_s_setprio(0);                                       \
    }                                                                        \
} while (0)

    // prologue: tiles 0 and 1 in flight; wait tile 0 (4 newest outstanding)
    STAGE(0, 0);
    STAGE(1, 1);
    asm volatile("s_waitcnt vmcnt(4)" ::: "memory");
    __builtin_amdgcn_s_barrier();

    for (int kt = 0; kt < 16; ++kt) {
        const int cur = kt & 1;
        if (cur == 0) COMPUTE(0); else COMPUTE(1);
        asm volatile("" ::: "memory");
        __builtin_amdgcn_s_barrier();          // all waves done reading buf cur
        if (kt < 14) {
            if (cur == 0) STAGE(kt + 2, 0); else STAGE(kt + 2, 1);
            asm volatile("s_waitcnt vmcnt(4)" ::: "memory");  // tile kt+1 resident
        } else if (kt == 14) {
            asm volatile("s_waitcnt vmcnt(0)" ::: "memory");  // drain tile 15
        }
        __builtin_amdgcn_s_barrier();
    }

    // ---- epilogue: bias, scale, store ----
#pragma unroll
    for (int mt = 0; mt < 8; mt++) {
#pragma unroll
        for (int nt = 0; nt < 4; nt++) {
            const int n = n0 + (wc << 6) + (nt << 4) + ln;
            const float bv = bias[n];
            const int mbase = m0 + (wr << 7) + (mt << 4) + (g << 2);
            if (OMODE == 0) {
#pragma unroll
                for (int r = 0; r < 4; r++) {
                    const int m = mbase + r;
                    const int b = m >> 6, tt = m & 63, hh = n >> 5, d = n & 31;
                    ((u16*)outp)[((size_t)(b * 16 + hh) * 64 + tt) * 32 + d] =
                        (u16)bfc((acc[mt][nt][r] + bv) * scale);
                }
            } else if (OMODE == 1) {
                short4_t hq;
#pragma unroll
                for (int r = 0; r < 4; r++) hq[r] = bfc((acc[mt][nt][r] + bv) * scale);
                const int b = mbase >> 6, tt = mbase & 63, hh = n >> 5, d = n & 31;
                *(short4_t*)&((u16*)outp)[((size_t)(b * 16 + hh) * 32 + d) * 64 + tt] = hq;
            } else {
#pragma unroll
                for (int r = 0; r < 4; r++) {
                    const int m = mbase + r;
                    ((float*)outp)[(size_t)m * 512 + n] = (acc[mt][nt][r] + bv) * scale;
                }
            }
        }
    }
#undef STAGE
#undef COMPUTE
}

// ---------------------------------------------------------------------------
// Attention: 4 waves/block, one (b,h) per wave. S^T = K·Q^T via mfma(K,Q);
// softmax over j = local reduce + shfl_xor 16/32; P -> private LDS region
// bf16 [i][j] XOR-swizzled; O^T = V^T·P.
// qh,kh: [b][h][t][d] bf16 ; vt: [b][h][d][t] bf16 ; x out: [b][t][h*32+d] bf16
// ---------------------------------------------------------------------------
__global__ __launch_bounds__(256) void attn_kernel(
        const u16* __restrict__ qh, const u16* __restrict__ kh,
        const u16* __restrict__ vt, const float* __restrict__ cwb,
        u16* __restrict__ xout)
{
    __shared__ __align__(16) u16 P[16384];   // 4 waves x 8 KB

    const int wv = threadIdx.x >> 6;
    const int bid = (blockIdx.x << 2) + wv;     // b*16 + h
    const int b = bid >> 4, h = bid & 15, w = b & 63;
    const int lane = threadIdx.x & 63, g = lane >> 4, ln = lane & 15;
    const size_t base = (size_t)bid * 2048;
    u16* Pw = &P[wv << 12];

    bf16x8 kf[4], qf[4];
#pragma unroll
    for (int mt = 0; mt < 4; mt++)
        kf[mt] = *(const bf16x8*)&kh[base + (mt * 16 + ln) * 32 + g * 8];
#pragma unroll
    for (int nt = 0; nt < 4; nt++)
        qf[nt] = *(const bf16x8*)&qh[base + (nt * 16 + ln) * 32 + g * 8];

    f32x4 acc[4][4];   // acc[mt][nt]: rows j = mt*16+g*4+r, cols i = nt*16+ln
#pragma unroll
    for (int i = 0; i < 4; i++)
#pragma unroll
        for (int j = 0; j < 4; j++) acc[i][j] = {0.f, 0.f, 0.f, 0.f};

#pragma unroll
    for (int mt = 0; mt < 4; mt++)
#pragma unroll
        for (int nt = 0; nt < 4; nt++)
            acc[mt][nt] = __builtin_amdgcn_mfma_f32_16x16x32_bf16(
                kf[mt], qf[nt], acc[mt][nt], 0, 0, 0);

    const float* cw = cwb + (size_t)(w * 16 + h) * 4096;
#pragma unroll
    for (int nt = 0; nt < 4; nt++) {
        const int i = nt * 16 + ln;
#pragma unroll
        for (int mt = 0; mt < 4; mt++) {
            const float4 bm = *(const float4*)&cw[i * 64 + mt * 16 + (g << 2)];
            acc[mt][nt][0] += bm.x; acc[mt][nt][1] += bm.y;
            acc[mt][nt][2] += bm.z; acc[mt][nt][3] += bm.w;
        }
    }

#pragma unroll
    for (int nt = 0; nt < 4; nt++) {
        float mx = acc[0][nt][0];
#pragma unroll
        for (int mt = 0; mt < 4; mt++)
#pragma unroll
            for (int r = 0; r < 4; r++) mx = fmaxf(mx, acc[mt][nt][r]);
        mx = fmaxf(mx, __shfl_xor(mx, 16));
        mx = fmaxf(mx, __shfl_xor(mx, 32));
        float sum = 0.f;
#pragma unroll
        for (int mt = 0; mt < 4; mt++)
#pragma unroll
            for (int r = 0; r < 4; r++) {
                const float p = __expf(acc[mt][nt][r] - mx);
                acc[mt][nt][r] = p;
                sum += p;
            }
        sum += __shfl_xor(sum, 16);
        sum += __shfl_xor(sum, 32);
        const float rs = 1.0f / sum;
        const int i = nt * 16 + ln;
#pragma unroll
        for (int mt = 0; mt < 4; mt++) {
            short4_t hq;
#pragma unroll
            for (int r = 0; r < 4; r++) hq[r] = bfc(acc[mt][nt][r] * rs);
            const int idx = (i * 64 + mt * 16 + (g << 2)) ^ ((i & 7) << 3);
            *(short4_t*)&Pw[idx] = hq;
        }
    }
    __syncthreads();

    f32x4 oacc[2][4];
#pragma unroll
    for (int i = 0; i < 2; i++)
#pragma unroll
        for (int j = 0; j < 4; j++) oacc[i][j] = {0.f, 0.f, 0.f, 0.f};

#pragma unroll
    for (int ks = 0; ks < 2; ks++) {
        bf16x8 vf[2], pf[4];
#pragma unroll
        for (int mt = 0; mt < 2; mt++)
            vf[mt] = *(const bf16x8*)&vt[base + (mt * 16 + ln) * 64 + ks * 32 + g * 8];
#pragma unroll
        for (int nt = 0; nt < 4; nt++) {
            const int i = nt * 16 + ln;
            pf[nt] = *(const bf16x8*)&Pw[(i * 64 + ks * 32 + g * 8) ^ ((i & 7) << 3)];
        }
#pragma unroll
        for (int mt = 0; mt < 2; mt++)
#pragma unroll
            for (int nt = 0; nt < 4; nt++)
                oacc[mt][nt] = __builtin_amdgcn_mfma_f32_16x16x32_bf16(
                    vf[mt], pf[nt], oacc[mt][nt], 0, 0, 0);
    }

#pragma unroll
    for (int mt = 0; mt < 2; mt++) {
#pragma unroll
        for (int nt = 0; nt < 4; nt++) {
            const int i = nt * 16 + ln, d0 = mt * 16 + (g << 2);
            short4_t hq;
#pragma unroll
            for (int r = 0; r < 4; r++) hq[r] = bfc(oacc[mt][nt][r]);
            *(short4_t*)&xout[((size_t)b * 64 + i) * 512 + h * 32 + d0] = hq;
        }
    }
}

// ---------------------------------------------------------------------------
extern "C" void kernel_launch(void* const* d_in, const int* in_sizes, int n_in,
                              void* d_out, int out_size, void* d_ws, size_t ws_size,
                              hipStream_t stream) {
    const float* q    = (const float*)d_in[0];
    const float* k    = (const float*)d_in[1];
    const float* v    = (const float*)d_in[2];
    const float* mask = (const float*)d_in[3];
    const float* Wq   = (const float*)d_in[4];
    const float* bq   = (const float*)d_in[5];
    const float* Wk   = (const float*)d_in[6];
    const float* bk   = (const float*)d_in[7];
    const float* Wv   = (const float*)d_in[8];
    const float* bv   = (const float*)d_in[9];
    const float* Wp   = (const float*)d_in[10];
    const float* bp   = (const float*)d_in[11];
    const float* bias_table = (const float*)d_in[12];
    float* out = (float*)d_out;

    // ws layout (bytes): t0 (act bf16 / attn out) | qh | kh | vt | cwb | 4x W
    char* ws = (char*)d_ws;
    u16*   t0  = (u16*)(ws);
    u16*   qh  = (u16*)(ws + 67108864);
    u16*   kh  = (u16*)(ws + 134217728);
    u16*   vt  = (u16*)(ws + 201326592);
    float* cwb = (float*)(ws + 268435456);
    u16*   wqb = (u16*)(ws + 285212672);
    u16*   wkb = (u16*)(ws + 285736960);
    u16*   wvb = (u16*)(ws + 286261248);
    u16*   wpb = (u16*)(ws + 286785536);

    const int n8_act = (1024 * 64 * 512) / 8;   // 4,194,304

    cwb_kernel<<<1024, 256, 0, stream>>>(bias_table, mask, cwb);
    wcvt_kernel<<<dim3(128, 4), 256, 0, stream>>>(Wq, Wk, Wv, Wp, wqb, wkb, wvb, wpb);

    cvt_kernel<<<n8_act / 256, 256, 0, stream>>>(q, t0, n8_act);
    gemm256<0><<<512, 512, 0, stream>>>(t0, wqb, bq, SCALE_Q, (void*)qh);

    cvt_kernel<<<n8_act / 256, 256, 0, stream>>>(k, t0, n8_act);
    gemm256<0><<<512, 512, 0, stream>>>(t0, wkb, bk, 1.0f, (void*)kh);

    cvt_kernel<<<n8_act / 256, 256, 0, stream>>>(v, t0, n8_act);
    gemm256<1><<<512, 512, 0, stream>>>(t0, wvb, bv, 1.0f, (void*)vt);

    attn_kernel<<<4096, 256, 0, stream>>>(qh, kh, vt, cwb, t0);

    gemm256<2><<<512, 512, 0, stream>>>(t0, wpb, bp, 1.0f, (void*)out);
}

// Round 8
// 427.600 us; speedup vs baseline: 2.0888x; 1.6402x over previous
//
#include <hip/hip_runtime.h>
#include <hip/hip_bf16.h>

typedef __attribute__((ext_vector_type(4))) float  f32x4;
typedef __attribute__((ext_vector_type(8))) short  bf16x8;
typedef __attribute__((ext_vector_type(4))) short  short4_t;
typedef unsigned short u16;

#define SCALE_Q 0.17677669529663687f   // 32^-0.5

// native RNE float->bf16 (compiler packs pairs into v_cvt_pk_bf16_f32)
__device__ __forceinline__ short bfc(float f) {
    __bf16 b = (__bf16)f;
    union { __bf16 b; short s; } u; u.b = b; return u.s;
}

__device__ __forceinline__ bf16x8 pack8(f32x4 a, f32x4 b) {
    bf16x8 o;
    o[0] = bfc(a[0]); o[1] = bfc(a[1]); o[2] = bfc(a[2]); o[3] = bfc(a[3]);
    o[4] = bfc(b[0]); o[5] = bfc(b[1]); o[6] = bfc(b[2]); o[7] = bfc(b[3]);
    return o;
}

__device__ __forceinline__ void load_lds16(const void* g, void* l) {
    __builtin_amdgcn_global_load_lds(
        (const __attribute__((address_space(1))) void*)g,
        (__attribute__((address_space(3))) void*)l, 16, 0, 0);
}

// ---------------------------------------------------------------------------
// All four 512x512 weights fp32->bf16 in one launch.
// ---------------------------------------------------------------------------
__global__ __launch_bounds__(256) void wcvt_kernel(
        const float* __restrict__ w0, const float* __restrict__ w1,
        const float* __restrict__ w2, const float* __restrict__ w3,
        u16* __restrict__ d0, u16* __restrict__ d1,
        u16* __restrict__ d2, u16* __restrict__ d3)
{
    const float* s = (blockIdx.y == 0) ? w0 : (blockIdx.y == 1) ? w1
                   : (blockIdx.y == 2) ? w2 : w3;
    u16* d = (blockIdx.y == 0) ? d0 : (blockIdx.y == 1) ? d1
           : (blockIdx.y == 2) ? d2 : d3;
    const int i = blockIdx.x * 256 + threadIdx.x;   // 32768 per matrix
    const float4* sp = (const float4*)s + (size_t)i * 2;
    const float4 a = sp[0], b = sp[1];
    bf16x8 o;
    o[0] = bfc(a.x); o[1] = bfc(a.y); o[2] = bfc(a.z); o[3] = bfc(a.w);
    o[4] = bfc(b.x); o[5] = bfc(b.y); o[6] = bfc(b.z); o[7] = bfc(b.w);
    *((bf16x8*)d + i) = o;
}

// ---------------------------------------------------------------------------
// cwb[w][h][i][j] = bias_table[REL_IDX[i][j]][h] + mask[w][i][j]   (fp32)
// ---------------------------------------------------------------------------
__global__ __launch_bounds__(256) void cwb_kernel(
        const float* __restrict__ bias_table,   // [225][16]
        const float* __restrict__ mask,         // [64][64][64]
        float* __restrict__ cwb)                // [64][16][64][64]
{
    const int wh = blockIdx.x;          // w*16 + h
    const int w = wh >> 4, h = wh & 15;
    for (int e = threadIdx.x; e < 4096; e += 256) {
        const int i = e >> 6, j = e & 63;
        const int rel = ((i >> 3) - (j >> 3) + 7) * 15 + (i & 7) - (j & 7) + 7;
        cwb[(size_t)wh * 4096 + e] = bias_table[rel * 16 + h] + mask[(size_t)w * 4096 + e];
    }
}

// ---------------------------------------------------------------------------
// QKV projection GEMM, fp32-A direct. C[65536,512] = A_f32 @ W_b16^T +b, *s.
// 128x128 tile, BK=32 (LDS: A fp32 16KB + B bf16 8KB = 24KB -> 6 blocks/CU),
// 4 waves (2x2), 16x16x32 bf16 MFMA, m97 2-barrier loop, global_load_lds 16B
// with pre-swizzled GLOBAL source (LDS dest linear).
//   A swizzle: 4-f32 block blk of row r at slot (blk ^ (r&7))   [8 slots/row]
//   B swizzle: 8-b16 block blk of row r at slot (blk ^ (r&3))   [4 slots/row]
// OMODE: 0 = bf16 out [b][h][t][d]; 1 = bf16 out [b][h][d][t]
// ---------------------------------------------------------------------------
template<int OMODE>
__global__ __launch_bounds__(256, 4) void gemm_f32a(
        const float* __restrict__ A, const u16* __restrict__ Wb,
        const float* __restrict__ bias, float scale, void* __restrict__ outp)
{
    __shared__ __align__(16) float Asf[4096];   // [128][32] f32, swizzled
    __shared__ __align__(16) u16   Bs[4096];    // [128][32] b16, swizzled

    // XCD swizzle: 2048 wgs, 8 XCDs, 256 contiguous per XCD
    const int wg = (blockIdx.x & 7) * 256 + (blockIdx.x >> 3);
    const int m0 = (wg >> 2) << 7;
    const int n0 = (wg & 3) << 7;

    const int t = threadIdx.x;
    const int lane = t & 63, wv = t >> 6;
    const int g = lane >> 4, ln = lane & 15;
    const int wr = wv >> 1, wc = wv & 1;

    const float* Ab = A  + (size_t)m0 * 512;
    const u16*   Bb = Wb + (size_t)n0 * 512;

    f32x4 acc[4][4];
#pragma unroll
    for (int i = 0; i < 4; i++)
#pragma unroll
        for (int j = 0; j < 4; j++) acc[i][j] = {0.f, 0.f, 0.f, 0.f};

    for (int k0 = 0; k0 < 512; k0 += 32) {
        // ---- stage A (128x32 fp32 = 1024 16B-blocks) ----
#pragma unroll
        for (int c = 0; c < 4; c++) {
            const int bi  = (c << 8) + t;
            const int row = bi >> 3, blk = bi & 7;
            const int col = (blk ^ (row & 7)) << 2;
            load_lds16(Ab + (size_t)row * 512 + k0 + col, &Asf[bi << 2]);
        }
        // ---- stage B (128x32 bf16 = 512 16B-blocks) ----
#pragma unroll
        for (int c = 0; c < 2; c++) {
            const int bi  = (c << 8) + t;
            const int row = bi >> 2, blk = bi & 3;
            const int col = (blk ^ (row & 3)) << 3;
            load_lds16(Bb + (size_t)row * 512 + k0 + col, &Bs[bi << 3]);
        }
        __syncthreads();   // drains vmcnt(0)

        bf16x8 af[4], bfr[4];
#pragma unroll
        for (int mt = 0; mt < 4; mt++) {
            const int rm = (wr << 6) + (mt << 4) + ln;
            const int p0 = ((g << 1)    ) ^ (rm & 7);
            const int p1 = ((g << 1) + 1) ^ (rm & 7);
            const f32x4 lo = *(const f32x4*)&Asf[(rm << 5) + (p0 << 2)];
            const f32x4 hi = *(const f32x4*)&Asf[(rm << 5) + (p1 << 2)];
            af[mt] = pack8(lo, hi);
        }
#pragma unroll
        for (int nt = 0; nt < 4; nt++) {
            const int rn = (wc << 6) + (nt << 4) + ln;
            bfr[nt] = *(const bf16x8*)&Bs[(rn << 5) + ((g ^ (rn & 3)) << 3)];
        }
#pragma unroll
        for (int mt = 0; mt < 4; mt++)
#pragma unroll
            for (int nt = 0; nt < 4; nt++)
                acc[mt][nt] = __builtin_amdgcn_mfma_f32_16x16x32_bf16(
                    af[mt], bfr[nt], acc[mt][nt], 0, 0, 0);
        __syncthreads();
    }

    // ---- epilogue: bias, scale, store ----
#pragma unroll
    for (int mt = 0; mt < 4; mt++) {
#pragma unroll
        for (int nt = 0; nt < 4; nt++) {
            const int n = n0 + (wc << 6) + (nt << 4) + ln;
            const float bv = bias[n];
            const int mbase = m0 + (wr << 6) + (mt << 4) + (g << 2);
            if (OMODE == 0) {
#pragma unroll
                for (int r = 0; r < 4; r++) {
                    const int m = mbase + r;
                    const int b = m >> 6, tt = m & 63, hh = n >> 5, d = n & 31;
                    ((u16*)outp)[((size_t)(b * 16 + hh) * 64 + tt) * 32 + d] =
                        (u16)bfc((acc[mt][nt][r] + bv) * scale);
                }
            } else {
                short4_t hq;
#pragma unroll
                for (int r = 0; r < 4; r++) hq[r] = bfc((acc[mt][nt][r] + bv) * scale);
                const int b = mbase >> 6, tt = mbase & 63, hh = n >> 5, d = n & 31;
                *(short4_t*)&((u16*)outp)[((size_t)(b * 16 + hh) * 32 + d) * 64 + tt] = hq;
            }
        }
    }
}

// ---------------------------------------------------------------------------
// Final projection GEMM (bf16 A): r2's proven m97-structure, BK=64, 32KB LDS.
// out fp32 [m][n].
// ---------------------------------------------------------------------------
__global__ __launch_bounds__(256) void gemm_bf16(
        const u16* __restrict__ A, const u16* __restrict__ Wb,
        const float* __restrict__ bias, float* __restrict__ outp)
{
    __shared__ __align__(16) u16 As[8192];   // [128][64] swizzled
    __shared__ __align__(16) u16 Bs[8192];

    const int wg = (blockIdx.x & 7) * 256 + (blockIdx.x >> 3);
    const int m0 = (wg >> 2) << 7;
    const int n0 = (wg & 3) << 7;

    const int t = threadIdx.x;
    const int lane = t & 63, wv = t >> 6;
    const int g = lane >> 4, ln = lane & 15;
    const int wr = wv >> 1, wc = wv & 1;
    const int wbase = wv << 6;

    f32x4 acc[4][4];
#pragma unroll
    for (int i = 0; i < 4; i++)
#pragma unroll
        for (int j = 0; j < 4; j++) acc[i][j] = {0.f, 0.f, 0.f, 0.f};

    const u16* Abase = A  + (size_t)m0 * 512;
    const u16* Bbase = Wb + (size_t)n0 * 512;

    for (int k0 = 0; k0 < 512; k0 += 64) {
#pragma unroll
        for (int c = 0; c < 4; c++) {
            const int bi  = (c << 8) + wbase + lane;      // 16B-block 0..1023
            const int row = bi >> 3;
            const int cbs = (bi & 7) ^ (row & 7);
            const size_t go = (size_t)row * 512 + k0 + (cbs << 3);
            load_lds16(Abase + go, &As[((c << 8) + wbase) << 3]);
            load_lds16(Bbase + go, &Bs[((c << 8) + wbase) << 3]);
        }
        __syncthreads();
#pragma unroll
        for (int ks = 0; ks < 2; ks++) {
            bf16x8 af[4], bfr[4];
#pragma unroll
            for (int mt = 0; mt < 4; mt++) {
                const int row = (wr << 6) + (mt << 4) + ln;
                af[mt] = *(const bf16x8*)&As[(row << 6) + ((((ks << 2) + g) ^ (row & 7)) << 3)];
            }
#pragma unroll
            for (int nt = 0; nt < 4; nt++) {
                const int row = (wc << 6) + (nt << 4) + ln;
                bfr[nt] = *(const bf16x8*)&Bs[(row << 6) + ((((ks << 2) + g) ^ (row & 7)) << 3)];
            }
#pragma unroll
            for (int mt = 0; mt < 4; mt++)
#pragma unroll
                for (int nt = 0; nt < 4; nt++)
                    acc[mt][nt] = __builtin_amdgcn_mfma_f32_16x16x32_bf16(
                        af[mt], bfr[nt], acc[mt][nt], 0, 0, 0);
        }
        __syncthreads();
    }

#pragma unroll
    for (int mt = 0; mt < 4; mt++) {
#pragma unroll
        for (int nt = 0; nt < 4; nt++) {
            const int n = n0 + (wc << 6) + (nt << 4) + ln;
            const float bv = bias[n];
            const int mbase = m0 + (wr << 6) + (mt << 4) + (g << 2);
#pragma unroll
            for (int r = 0; r < 4; r++) {
                const int m = mbase + r;
                outp[(size_t)m * 512 + n] = acc[mt][nt][r] + bv;
            }
        }
    }
}

// ---------------------------------------------------------------------------
// Attention: 4 waves/block, one (b,h) per wave. S^T = K·Q^T via mfma(K,Q);
// softmax over j = local reduce + shfl_xor 16/32; P -> private LDS region
// bf16 [i][j] XOR-swizzled; O^T = V^T·P.
// qh,kh: [b][h][t][d] bf16 ; vt: [b][h][d][t] bf16 ; x out: [b][t][h*32+d] bf16
// ---------------------------------------------------------------------------
__global__ __launch_bounds__(256) void attn_kernel(
        const u16* __restrict__ qh, const u16* __restrict__ kh,
        const u16* __restrict__ vt, const float* __restrict__ cwb,
        u16* __restrict__ xout)
{
    __shared__ __align__(16) u16 P[16384];   // 4 waves x 8 KB

    const int wv = threadIdx.x >> 6;
    const int bid = (blockIdx.x << 2) + wv;     // b*16 + h
    const int b = bid >> 4, h = bid & 15, w = b & 63;
    const int lane = threadIdx.x & 63, g = lane >> 4, ln = lane & 15;
    const size_t base = (size_t)bid * 2048;
    u16* Pw = &P[wv << 12];

    bf16x8 kf[4], qf[4];
#pragma unroll
    for (int mt = 0; mt < 4; mt++)
        kf[mt] = *(const bf16x8*)&kh[base + (mt * 16 + ln) * 32 + g * 8];
#pragma unroll
    for (int nt = 0; nt < 4; nt++)
        qf[nt] = *(const bf16x8*)&qh[base + (nt * 16 + ln) * 32 + g * 8];

    f32x4 acc[4][4];   // acc[mt][nt]: rows j = mt*16+g*4+r, cols i = nt*16+ln
#pragma unroll
    for (int i = 0; i < 4; i++)
#pragma unroll
        for (int j = 0; j < 4; j++) acc[i][j] = {0.f, 0.f, 0.f, 0.f};

#pragma unroll
    for (int mt = 0; mt < 4; mt++)
#pragma unroll
        for (int nt = 0; nt < 4; nt++)
            acc[mt][nt] = __builtin_amdgcn_mfma_f32_16x16x32_bf16(
                kf[mt], qf[nt], acc[mt][nt], 0, 0, 0);

    const float* cw = cwb + (size_t)(w * 16 + h) * 4096;
#pragma unroll
    for (int nt = 0; nt < 4; nt++) {
        const int i = nt * 16 + ln;
#pragma unroll
        for (int mt = 0; mt < 4; mt++) {
            const float4 bm = *(const float4*)&cw[i * 64 + mt * 16 + (g << 2)];
            acc[mt][nt][0] += bm.x; acc[mt][nt][1] += bm.y;
            acc[mt][nt][2] += bm.z; acc[mt][nt][3] += bm.w;
        }
    }

#pragma unroll
    for (int nt = 0; nt < 4; nt++) {
        float mx = acc[0][nt][0];
#pragma unroll
        for (int mt = 0; mt < 4; mt++)
#pragma unroll
            for (int r = 0; r < 4; r++) mx = fmaxf(mx, acc[mt][nt][r]);
        mx = fmaxf(mx, __shfl_xor(mx, 16));
        mx = fmaxf(mx, __shfl_xor(mx, 32));
        float sum = 0.f;
#pragma unroll
        for (int mt = 0; mt < 4; mt++)
#pragma unroll
            for (int r = 0; r < 4; r++) {
                const float p = __expf(acc[mt][nt][r] - mx);
                acc[mt][nt][r] = p;
                sum += p;
            }
        sum += __shfl_xor(sum, 16);
        sum += __shfl_xor(sum, 32);
        const float rs = 1.0f / sum;
        const int i = nt * 16 + ln;
#pragma unroll
        for (int mt = 0; mt < 4; mt++) {
            short4_t hq;
#pragma unroll
            for (int r = 0; r < 4; r++) hq[r] = bfc(acc[mt][nt][r] * rs);
            const int idx = (i * 64 + mt * 16 + (g << 2)) ^ ((i & 7) << 3);
            *(short4_t*)&Pw[idx] = hq;
        }
    }
    __syncthreads();

    f32x4 oacc[2][4];
#pragma unroll
    for (int i = 0; i < 2; i++)
#pragma unroll
        for (int j = 0; j < 4; j++) oacc[i][j] = {0.f, 0.f, 0.f, 0.f};

#pragma unroll
    for (int ks = 0; ks < 2; ks++) {
        bf16x8 vf[2], pf[4];
#pragma unroll
        for (int mt = 0; mt < 2; mt++)
            vf[mt] = *(const bf16x8*)&vt[base + (mt * 16 + ln) * 64 + ks * 32 + g * 8];
#pragma unroll
        for (int nt = 0; nt < 4; nt++) {
            const int i = nt * 16 + ln;
            pf[nt] = *(const bf16x8*)&Pw[(i * 64 + ks * 32 + g * 8) ^ ((i & 7) << 3)];
        }
#pragma unroll
        for (int mt = 0; mt < 2; mt++)
#pragma unroll
            for (int nt = 0; nt < 4; nt++)
                oacc[mt][nt] = __builtin_amdgcn_mfma_f32_16x16x32_bf16(
                    vf[mt], pf[nt], oacc[mt][nt], 0, 0, 0);
    }

#pragma unroll
    for (int mt = 0; mt < 2; mt++) {
#pragma unroll
        for (int nt = 0; nt < 4; nt++) {
            const int i = nt * 16 + ln, d0 = mt * 16 + (g << 2);
            short4_t hq;
#pragma unroll
            for (int r = 0; r < 4; r++) hq[r] = bfc(oacc[mt][nt][r]);
            *(short4_t*)&xout[((size_t)b * 64 + i) * 512 + h * 32 + d0] = hq;
        }
    }
}

// ---------------------------------------------------------------------------
extern "C" void kernel_launch(void* const* d_in, const int* in_sizes, int n_in,
                              void* d_out, int out_size, void* d_ws, size_t ws_size,
                              hipStream_t stream) {
    const float* q    = (const float*)d_in[0];
    const float* k    = (const float*)d_in[1];
    const float* v    = (const float*)d_in[2];
    const float* mask = (const float*)d_in[3];
    const float* Wq   = (const float*)d_in[4];
    const float* bq   = (const float*)d_in[5];
    const float* Wk   = (const float*)d_in[6];
    const float* bk   = (const float*)d_in[7];
    const float* Wv   = (const float*)d_in[8];
    const float* bv   = (const float*)d_in[9];
    const float* Wp   = (const float*)d_in[10];
    const float* bp   = (const float*)d_in[11];
    const float* bias_table = (const float*)d_in[12];
    float* out = (float*)d_out;

    // ws layout (bytes): t0 (attn out bf16) | qh | kh | vt | cwb | 4x W bf16
    char* ws = (char*)d_ws;
    u16*   t0  = (u16*)(ws);
    u16*   qh  = (u16*)(ws + 67108864);
    u16*   kh  = (u16*)(ws + 134217728);
    u16*   vt  = (u16*)(ws + 201326592);
    float* cwb = (float*)(ws + 268435456);
    u16*   wqb = (u16*)(ws + 285212672);
    u16*   wkb = (u16*)(ws + 285736960);
    u16*   wvb = (u16*)(ws + 286261248);
    u16*   wpb = (u16*)(ws + 286785536);

    cwb_kernel<<<1024, 256, 0, stream>>>(bias_table, mask, cwb);
    wcvt_kernel<<<dim3(128, 4), 256, 0, stream>>>(Wq, Wk, Wv, Wp, wqb, wkb, wvb, wpb);

    gemm_f32a<0><<<2048, 256, 0, stream>>>(q, wqb, bq, SCALE_Q, (void*)qh);
    gemm_f32a<0><<<2048, 256, 0, stream>>>(k, wkb, bk, 1.0f,    (void*)kh);
    gemm_f32a<1><<<2048, 256, 0, stream>>>(v, wvb, bv, 1.0f,    (void*)vt);

    attn_kernel<<<4096, 256, 0, stream>>>(qh, kh, vt, cwb, t0);

    gemm_bf16<<<2048, 256, 0, stream>>>(t0, wpb, bp, out);
}